// Round 2
// baseline (1163.516 us; speedup 1.0000x reference)
//
#include <hip/hip_runtime.h>

#define B_TOTAL 65536
#define T_STEPS 28

typedef float f2 __attribute__((ext_vector_type(2)));

__device__ __forceinline__ float frcp(float x) { return __builtin_amdgcn_rcpf(x); }
__device__ __forceinline__ float sigf(float x) { return frcp(1.0f + __expf(-x)); }
__device__ __forceinline__ float tanhf_(float x) { return 2.0f * frcp(1.0f + __expf(-2.0f * x)) - 1.0f; }

// ---------------------------------------------------------------------------
// Repack weights into wave-uniform scalar-load-friendly rows in d_ws.
// Row format (132 floats): [b_i b_f b_g b_o][Wi 0..31][Wf 0..31][Wg 0..31][Wo 0..31]
//   enc row k (k=0..3):   inputs = [x(28), he_prev(4)]  -> W*[j<28]=Wih, W*[28+j]=Whh
//   dec row k (rows 4..31): inputs = [hd(28), z(4)]     -> W*[j<28]=Whh, W*[28+j]=Wih
// U rows at float offset 4224, stride 32: [bias][UW 28][pad 3]
// All gate sub-rows start at even dword offsets -> weight PAIRS are 8B aligned.
// ---------------------------------------------------------------------------
__global__ void repack_kernel(const float* __restrict__ eWih, const float* __restrict__ eWhh,
                              const float* __restrict__ eb,
                              const float* __restrict__ dWih, const float* __restrict__ dWhh,
                              const float* __restrict__ db,
                              const float* __restrict__ UW, const float* __restrict__ Ub,
                              float* __restrict__ w)
{
    const int p = threadIdx.x;
    for (int idx = p; idx < 4 * 132; idx += 256) {
        int k = idx / 132, r = idx % 132;
        float v;
        if (r < 4) v = eb[r * 4 + k];
        else {
            int g = (r - 4) / 32, j = (r - 4) % 32;
            v = (j < 28) ? eWih[(g * 4 + k) * 28 + j] : eWhh[(g * 4 + k) * 4 + (j - 28)];
        }
        w[k * 132 + r] = v;
    }
    for (int idx = p; idx < 28 * 132; idx += 256) {
        int k = idx / 132, r = idx % 132;
        float v;
        if (r < 4) v = db[r * 28 + k];
        else {
            int g = (r - 4) / 32, j = (r - 4) % 32;
            v = (j < 28) ? dWhh[(g * 28 + k) * 28 + j] : dWih[(g * 28 + k) * 4 + (j - 28)];
        }
        w[528 + k * 132 + r] = v;
    }
    for (int idx = p; idx < 10 * 32; idx += 256) {
        int c = idx / 32, r = idx % 32;
        float v = (r == 0) ? Ub[c] : ((r <= 28) ? UW[c * 28 + (r - 1)] : 0.f);
        w[4224 + c * 32 + r] = v;
    }
}

// ---------------------------------------------------------------------------
// LDS layout: one flat pool, byte offsets below. State tiles are [64 rows][32
// dwords] with an XOR pair-swizzle: logical (row, k) lives at dword
//   row*32 + (((k>>1) ^ (row&15))<<1 | (k&1))
// Properties: logical pairs (2j,2j+1) stay adjacent & 8B aligned ->
// ds_read_b64; a wave64 pair-read at fixed j is conflict-free (16 disjoint
// bank pairs); cross-row (i,k) staging access is ~conflict-free.
// ---------------------------------------------------------------------------
#define XB   0        // x(t) tile, 8192 B
#define HD0  8192     // decoder h, buffer 0
#define HD1  16384    // decoder h, buffer 1
#define HE   24576    // encoder h [2][4][64] floats, 2048 B

// One full timestep. P_ = t&1 (literal). HDC/HDN = byte base of current/next
// decoder-h tile (literals).
#define LSTM_STEP(T_, P_, HDC, HDN)                                             \
    {                                                                           \
        f2 in2[16];                                                             \
        _Pragma("unroll")                                                       \
        for (int jp = 0; jp < 14; jp++)                                         \
            in2[jp] = *(const f2*)(lb + XB + sb[jp]);                           \
        {                                                                       \
            const float* heP = (const float*)(lb + HE) + (P_) * 256;            \
            f2 ha, hb;                                                          \
            ha.x = heP[0 * 64 + lane]; ha.y = heP[1 * 64 + lane];               \
            hb.x = heP[2 * 64 + lane]; hb.y = heP[3 * 64 + lane];               \
            in2[14] = ha; in2[15] = hb;                                         \
        }                                                                       \
        {                                                                       \
            f2 a0, a1, a2, a3;                                                  \
            a0.x = wenc[0]; a0.y = 0.f;  a1.x = wenc[1]; a1.y = 0.f;            \
            a2.x = wenc[2]; a2.y = 0.f;  a3.x = wenc[3]; a3.y = 0.f;            \
            const f2* wg0 = (const f2*)(wenc + 4);                              \
            const f2* wg1 = (const f2*)(wenc + 36);                             \
            const f2* wg2 = (const f2*)(wenc + 68);                             \
            const f2* wg3 = (const f2*)(wenc + 100);                            \
            _Pragma("unroll")                                                   \
            for (int jp = 0; jp < 16; jp++) {                                   \
                a0 = __builtin_elementwise_fma(wg0[jp], in2[jp], a0);           \
                a1 = __builtin_elementwise_fma(wg1[jp], in2[jp], a1);           \
                a2 = __builtin_elementwise_fma(wg2[jp], in2[jp], a2);           \
                a3 = __builtin_elementwise_fma(wg3[jp], in2[jp], a3);           \
            }                                                                   \
            const float gi = a0.x + a0.y, gf = a1.x + a1.y;                     \
            const float gg = a2.x + a2.y, go = a3.x + a3.y;                     \
            ce = sigf(gf) * ce + sigf(gi) * tanhf_(gg);                         \
            ((float*)(lb + HE))[(1 - (P_)) * 256 + s * 64 + lane] =             \
                sigf(go) * tanhf_(ce);                                          \
        }                                                                       \
        __syncthreads(); /* barrier A: he(t) ready, xBuf(t) reads done */       \
        float xr[7];                                                            \
        if ((T_) < T_STEPS - 1) {                                               \
            _Pragma("unroll")                                                   \
            for (int q = 0; q < 7; q++)                                         \
                xr[q] = xblk[goff[q] + ((T_) + 1) * 28];                        \
        }                                                                       \
        _Pragma("unroll")                                                       \
        for (int jp = 0; jp < 14; jp++)                                         \
            in2[jp] = *(const f2*)(lb + (HDC) + sb[jp]);                        \
        {                                                                       \
            const float* heN = (const float*)(lb + HE) + (1 - (P_)) * 256;      \
            f2 za, zb;                                                          \
            za.x = heN[0 * 64 + lane]; za.y = heN[1 * 64 + lane];               \
            zb.x = heN[2 * 64 + lane]; zb.y = heN[3 * 64 + lane];               \
            in2[14] = za; in2[15] = zb;                                         \
        }                                                                       \
        _Pragma("unroll")                                                       \
        for (int r = 0; r < 7; r++) {                                           \
            const float* __restrict__ wrow = w + 528 + (s * 7 + r) * 132;       \
            f2 a0, a1, a2, a3;                                                  \
            a0.x = wrow[0]; a0.y = 0.f;  a1.x = wrow[1]; a1.y = 0.f;            \
            a2.x = wrow[2]; a2.y = 0.f;  a3.x = wrow[3]; a3.y = 0.f;            \
            const f2* wg0 = (const f2*)(wrow + 4);                              \
            const f2* wg1 = (const f2*)(wrow + 36);                             \
            const f2* wg2 = (const f2*)(wrow + 68);                             \
            const f2* wg3 = (const f2*)(wrow + 100);                            \
            _Pragma("unroll")                                                   \
            for (int jp = 0; jp < 16; jp++) {                                   \
                a0 = __builtin_elementwise_fma(wg0[jp], in2[jp], a0);           \
                a1 = __builtin_elementwise_fma(wg1[jp], in2[jp], a1);           \
                a2 = __builtin_elementwise_fma(wg2[jp], in2[jp], a2);           \
                a3 = __builtin_elementwise_fma(wg3[jp], in2[jp], a3);           \
            }                                                                   \
            const float gi = a0.x + a0.y, gf = a1.x + a1.y;                     \
            const float gg = a2.x + a2.y, go = a3.x + a3.y;                     \
            const float cc = sigf(gf) * cd[r] + sigf(gi) * tanhf_(gg);          \
            cd[r] = cc;                                                         \
            *(float*)(lb + (HDN) + wb[r]) = sigf(go) * tanhf_(cc);              \
        }                                                                       \
        if ((T_) < T_STEPS - 1) {                                               \
            _Pragma("unroll")                                                   \
            for (int q = 0; q < 7; q++)                                         \
                *(float*)(lb + XB + stb[q]) = xr[q];                            \
        }                                                                       \
        __syncthreads(); /* barrier B: hd(t) + xBuf(t+1) complete */            \
        _Pragma("unroll")                                                       \
        for (int q = 0; q < 7; q++)                                             \
            oblk[goff[q] + (T_) * 28] = *(const float*)(lb + (HDN) + stb[q]);   \
    }

__global__ __launch_bounds__(256, 4)
void lstm_main(const float* __restrict__ x, const float* __restrict__ w,
               float* __restrict__ out, float* __restrict__ pred)
{
    __shared__ float ldsPool[3 * 2048 + 512];   // 26624 B
    char* lb = (char*)ldsPool;

    const int tid  = threadIdx.x;
    const int lane = tid & 63;
    const int s    = __builtin_amdgcn_readfirstlane(tid >> 6);
    const int e0   = blockIdx.x * 64;
    const int e    = e0 + lane;
    const int L    = lane & 15;

    // per-lane swizzled pair-read offsets (bytes): pair jp of row `lane`
    int sb[16];
#pragma unroll
    for (int jp = 0; jp < 16; jp++) sb[jp] = lane * 128 + ((jp ^ L) << 3);

    // decoder write offsets for rows k = s*7+r
    int wb[7];
#pragma unroll
    for (int r = 0; r < 7; r++) {
        int k = s * 7 + r;
        wb[r] = lane * 128 + (((((k >> 1) ^ L) << 1) | (k & 1)) << 2);
    }

    // block-coalesced staging map: idx = tid+256q -> (i = idx/28, k = idx%28)
    int goff[7], stb[7];
#pragma unroll
    for (int q = 0; q < 7; q++) {
        int idx = tid + 256 * q;
        int i = idx / 28;
        int k = idx - 28 * i;
        goff[q] = i * 784 + k;
        stb[q]  = i * 128 + (((((k >> 1) ^ (i & 15)) << 1) | (k & 1)) << 2);
    }

    const float* __restrict__ xblk = x + (size_t)e0 * 784;
    float* __restrict__ oblk       = out + (size_t)e0 * 784;

    // ---- prologue: stage x(0), zero hd0 + he[0] ----
#pragma unroll
    for (int q = 0; q < 7; q++)
        *(float*)(lb + XB + stb[q]) = xblk[goff[q]];
    for (int i = tid; i < 2048; i += 256) ((float*)(lb + HD0))[i] = 0.f;
    ((float*)(lb + HE))[tid] = 0.f;   // heBuf[0][*][*]
    __syncthreads();

    const float* __restrict__ wenc = w + s * 132;

    float ce = 0.f;
    float cd[7];
#pragma unroll
    for (int r = 0; r < 7; r++) cd[r] = 0.f;

    for (int tt = 0; tt < T_STEPS; tt += 2) {
        LSTM_STEP(tt,     0, HD0, HD1)
        LSTM_STEP(tt + 1, 1, HD1, HD0)
    }

    // ---- final projection + softmax (wave 0 only); last write was HD0 ----
    if (s == 0) {
        float hf[28];
#pragma unroll
        for (int jj = 0; jj < 14; jj++) {
            f2 hp = *(const f2*)(lb + HD0 + sb[jj]);
            hf[2 * jj] = hp.x; hf[2 * jj + 1] = hp.y;
        }
        float lg[10];
#pragma unroll
        for (int c = 0; c < 10; c++) {
            const float* __restrict__ ur = w + 4224 + c * 32;
            float a = ur[0];
#pragma unroll
            for (int j = 0; j < 28; j++) a = fmaf(ur[1 + j], hf[j], a);
            lg[c] = a;
        }
        float m = lg[0];
#pragma unroll
        for (int c = 1; c < 10; c++) m = fmaxf(m, lg[c]);
        float sum = 0.f;
#pragma unroll
        for (int c = 0; c < 10; c++) { lg[c] = __expf(lg[c] - m); sum += lg[c]; }
        const float inv = frcp(sum);
        float* __restrict__ pr = pred + (size_t)e * 10;
#pragma unroll
        for (int c = 0; c < 10; c++) pr[c] = lg[c] * inv;
    }
}

extern "C" void kernel_launch(void* const* d_in, const int* in_sizes, int n_in,
                              void* d_out, int out_size, void* d_ws, size_t ws_size,
                              hipStream_t stream) {
    const float* x    = (const float*)d_in[0];
    const float* eWih = (const float*)d_in[1];
    const float* eWhh = (const float*)d_in[2];
    const float* eb   = (const float*)d_in[3];
    const float* dWih = (const float*)d_in[4];
    const float* dWhh = (const float*)d_in[5];
    const float* db   = (const float*)d_in[6];
    const float* UW   = (const float*)d_in[7];
    const float* Ub   = (const float*)d_in[8];

    float* w    = (float*)d_ws;                      // 4544 floats used
    float* out  = (float*)d_out;
    float* pred = out + (size_t)B_TOTAL * T_STEPS * 28;

    repack_kernel<<<dim3(1), dim3(256), 0, stream>>>(eWih, eWhh, eb, dWih, dWhh, db, UW, Ub, w);
    lstm_main<<<dim3(B_TOTAL / 64), dim3(256), 0, stream>>>(x, w, out, pred);
}

// Round 3
// 927.036 us; speedup vs baseline: 1.2551x; 1.2551x over previous
//
#include <hip/hip_runtime.h>

#define B_TOTAL 65536
#define T_STEPS 28

typedef float f2 __attribute__((ext_vector_type(2)));

__device__ __forceinline__ float frcp(float x) { return __builtin_amdgcn_rcpf(x); }
__device__ __forceinline__ float sigf(float x) { return frcp(1.0f + __expf(-x)); }
__device__ __forceinline__ float tanhf_(float x) { return 2.0f * frcp(1.0f + __expf(-2.0f * x)) - 1.0f; }

// ---------------------------------------------------------------------------
// Repack weights into wave-uniform rows in d_ws.
// Row format (132 floats): [b_i b_f b_g b_o][Wi 0..31][Wf 0..31][Wg 0..31][Wo 0..31]
//   enc row k (k=0..3):   inputs = [x(28), he_prev(4)]  -> W*[j<28]=Wih, W*[28+j]=Whh
//   dec row k (rows 4..31): inputs = [hd(28), z(4)]     -> W*[j<28]=Whh, W*[28+j]=Wih
// U rows at float offset 4224, stride 32: [bias][UW 28][pad 3]
// Every gate sub-row starts at an even dword -> all weight PAIRS 8B aligned.
// ---------------------------------------------------------------------------
__global__ void repack_kernel(const float* __restrict__ eWih, const float* __restrict__ eWhh,
                              const float* __restrict__ eb,
                              const float* __restrict__ dWih, const float* __restrict__ dWhh,
                              const float* __restrict__ db,
                              const float* __restrict__ UW, const float* __restrict__ Ub,
                              float* __restrict__ w)
{
    const int p = threadIdx.x;
    for (int idx = p; idx < 4 * 132; idx += 256) {
        int k = idx / 132, r = idx % 132;
        float v;
        if (r < 4) v = eb[r * 4 + k];
        else {
            int g = (r - 4) / 32, j = (r - 4) % 32;
            v = (j < 28) ? eWih[(g * 4 + k) * 28 + j] : eWhh[(g * 4 + k) * 4 + (j - 28)];
        }
        w[k * 132 + r] = v;
    }
    for (int idx = p; idx < 28 * 132; idx += 256) {
        int k = idx / 132, r = idx % 132;
        float v;
        if (r < 4) v = db[r * 28 + k];
        else {
            int g = (r - 4) / 32, j = (r - 4) % 32;
            v = (j < 28) ? dWhh[(g * 28 + k) * 28 + j] : dWih[(g * 28 + k) * 4 + (j - 28)];
        }
        w[528 + k * 132 + r] = v;
    }
    for (int idx = p; idx < 10 * 32; idx += 256) {
        int c = idx / 32, r = idx % 32;
        float v = (r == 0) ? Ub[c] : ((r <= 28) ? UW[c * 28 + (r - 1)] : 0.f);
        w[4224 + c * 32 + r] = v;
    }
}

// ---------------------------------------------------------------------------
// LDS byte offsets. State tiles are [64 rows][30 dwords] (row stride 120 B,
// 8B-aligned rows; pair read at fixed j across 64 lanes is conflict-free).
// ---------------------------------------------------------------------------
#define XB   0        // x(t)           7680 B
#define HD0  7680     // decoder h, buf0
#define HD1  15360    // decoder h, buf1
#define HE   23040    // encoder h [2][64][4] floats, 2048 B
// total 25088 B

__global__ __launch_bounds__(256, 4)
void lstm_main(const float* __restrict__ x, const float* __restrict__ w,
               float* __restrict__ out, float* __restrict__ pred)
{
    __shared__ char lb[25088];

    const int tid  = threadIdx.x;
    const int lane = tid & 63;
    const int s    = __builtin_amdgcn_readfirstlane(tid >> 6);
    const int e0   = blockIdx.x * 64;

    // block-coalesced staging map: idx = tid+256q -> (i = idx/28, k = idx%28)
    int goff[7], stb[7];
#pragma unroll
    for (int q = 0; q < 7; q++) {
        int idx = tid + 256 * q;
        int i = idx / 28;
        int k = idx - 28 * i;
        goff[q] = i * 784 + k;     // float offset in x / out block
        stb[q]  = i * 120 + k * 4; // byte offset in [64][30] LDS tile
    }

    const float* __restrict__ xblk = x + (size_t)e0 * 784;
    float* __restrict__ oblk       = out + (size_t)e0 * 784;

    // ---- prologue: stage x(0), zero hd0 + he[0] ----
#pragma unroll
    for (int q = 0; q < 7; q++)
        *(float*)(lb + XB + stb[q]) = xblk[goff[q]];
    for (int i2 = tid; i2 < 1920; i2 += 256) ((float*)(lb + HD0))[i2] = 0.f;
    ((float*)(lb + HE))[tid] = 0.f;   // he phase 0: 256 floats
    __syncthreads();

    const float* __restrict__ wenc = w + s * 132;
    const char* xrow = lb + XB + lane * 120;

    float ce = 0.f;
    float cd[7];
#pragma unroll
    for (int r = 0; r < 7; r++) cd[r] = 0.f;

    int hdc = HD0, hdn = HD1;

    for (int t = 0; t < T_STEPS; ++t) {
        const int p = t & 1;

        // ---- issue x(t+1) prefetch early (lands in phase 4.5) ----
        float xr[7];
        if (t < T_STEPS - 1) {
#pragma unroll
            for (int q = 0; q < 7; q++)
                xr[q] = xblk[goff[q] + (t + 1) * 28];
        }

        // ---- encoder unit s ----
        {
            const f2* xp2 = (const f2*)xrow;
            const f2 hep0 = *(const f2*)(lb + HE + p * 1024 + lane * 16);
            const f2 hep1 = *(const f2*)(lb + HE + p * 1024 + lane * 16 + 8);
            const f2* wg0 = (const f2*)(wenc + 4);
            const f2* wg1 = (const f2*)(wenc + 36);
            const f2* wg2 = (const f2*)(wenc + 68);
            const f2* wg3 = (const f2*)(wenc + 100);
            f2 a0 = {wenc[0], 0.f}, a1 = {wenc[1], 0.f};
            f2 a2 = {wenc[2], 0.f}, a3 = {wenc[3], 0.f};
#pragma unroll
            for (int j = 0; j < 14; j++) {
                const f2 v = xp2[j];
                a0 = __builtin_elementwise_fma(wg0[j], v, a0);
                a1 = __builtin_elementwise_fma(wg1[j], v, a1);
                a2 = __builtin_elementwise_fma(wg2[j], v, a2);
                a3 = __builtin_elementwise_fma(wg3[j], v, a3);
            }
            a0 = __builtin_elementwise_fma(wg0[14], hep0, a0);
            a1 = __builtin_elementwise_fma(wg1[14], hep0, a1);
            a2 = __builtin_elementwise_fma(wg2[14], hep0, a2);
            a3 = __builtin_elementwise_fma(wg3[14], hep0, a3);
            a0 = __builtin_elementwise_fma(wg0[15], hep1, a0);
            a1 = __builtin_elementwise_fma(wg1[15], hep1, a1);
            a2 = __builtin_elementwise_fma(wg2[15], hep1, a2);
            a3 = __builtin_elementwise_fma(wg3[15], hep1, a3);
            const float gi = a0.x + a0.y, gf = a1.x + a1.y;
            const float gg = a2.x + a2.y, go = a3.x + a3.y;
            ce = sigf(gf) * ce + sigf(gi) * tanhf_(gg);
            *(float*)(lb + HE + (p ^ 1) * 1024 + lane * 16 + s * 4) =
                sigf(go) * tanhf_(ce);
        }
        __syncthreads();   // barrier A: he(t) ready; xBuf(t) reads done

        // ---- decoder rows s*7 .. s*7+6 ----
        {
            const f2 hz0 = *(const f2*)(lb + HE + (p ^ 1) * 1024 + lane * 16);
            const f2 hz1 = *(const f2*)(lb + HE + (p ^ 1) * 1024 + lane * 16 + 8);
            const f2* hc2 = (const f2*)(lb + hdc + lane * 120);
            f2 hv[14];
#pragma unroll
            for (int j = 0; j < 14; j++) hv[j] = hc2[j];
            char* hwr = lb + hdn + lane * 120 + s * 28;   // rows s*7..s*7+6
#pragma unroll
            for (int r = 0; r < 7; r++) {
                const float* __restrict__ wrow = w + 528 + (s * 7 + r) * 132;
                const f2* wg0 = (const f2*)(wrow + 4);
                const f2* wg1 = (const f2*)(wrow + 36);
                const f2* wg2 = (const f2*)(wrow + 68);
                const f2* wg3 = (const f2*)(wrow + 100);
                f2 a0 = {wrow[0], 0.f}, a1 = {wrow[1], 0.f};
                f2 a2 = {wrow[2], 0.f}, a3 = {wrow[3], 0.f};
#pragma unroll
                for (int j = 0; j < 14; j++) {
                    const f2 v = hv[j];
                    a0 = __builtin_elementwise_fma(wg0[j], v, a0);
                    a1 = __builtin_elementwise_fma(wg1[j], v, a1);
                    a2 = __builtin_elementwise_fma(wg2[j], v, a2);
                    a3 = __builtin_elementwise_fma(wg3[j], v, a3);
                }
                a0 = __builtin_elementwise_fma(wg0[14], hz0, a0);
                a1 = __builtin_elementwise_fma(wg1[14], hz0, a1);
                a2 = __builtin_elementwise_fma(wg2[14], hz0, a2);
                a3 = __builtin_elementwise_fma(wg3[14], hz0, a3);
                a0 = __builtin_elementwise_fma(wg0[15], hz1, a0);
                a1 = __builtin_elementwise_fma(wg1[15], hz1, a1);
                a2 = __builtin_elementwise_fma(wg2[15], hz1, a2);
                a3 = __builtin_elementwise_fma(wg3[15], hz1, a3);
                const float gi = a0.x + a0.y, gf = a1.x + a1.y;
                const float gg = a2.x + a2.y, go = a3.x + a3.y;
                const float cc = sigf(gf) * cd[r] + sigf(gi) * tanhf_(gg);
                cd[r] = cc;
                *(float*)(hwr + r * 4) = sigf(go) * tanhf_(cc);
            }
        }

        // ---- land x(t+1) (xBuf reads ended at barrier A) ----
        if (t < T_STEPS - 1) {
#pragma unroll
            for (int q = 0; q < 7; q++)
                *(float*)(lb + XB + stb[q]) = xr[q];
        }
        __syncthreads();   // barrier B: hd(t) + xBuf(t+1) complete

        // ---- coalesced out store ----
        {
            const char* hsrc = lb + hdn;
#pragma unroll
            for (int q = 0; q < 7; q++)
                oblk[goff[q] + t * 28] = *(const float*)(hsrc + stb[q]);
        }
        const int tmp = hdc; hdc = hdn; hdn = tmp;
    }

    // ---- final projection + softmax (wave 0 only); final h is in `hdc` ----
    if (s == 0) {
        float hf[28];
        const f2* hc2 = (const f2*)(lb + hdc + lane * 120);
#pragma unroll
        for (int j = 0; j < 14; j++) {
            const f2 hp = hc2[j];
            hf[2 * j] = hp.x; hf[2 * j + 1] = hp.y;
        }
        float lg[10];
#pragma unroll
        for (int c = 0; c < 10; c++) {
            const float* __restrict__ ur = w + 4224 + c * 32;
            float a = ur[0];
#pragma unroll
            for (int j = 0; j < 28; j++) a = fmaf(ur[1 + j], hf[j], a);
            lg[c] = a;
        }
        float m = lg[0];
#pragma unroll
        for (int c = 1; c < 10; c++) m = fmaxf(m, lg[c]);
        float sum = 0.f;
#pragma unroll
        for (int c = 0; c < 10; c++) { lg[c] = __expf(lg[c] - m); sum += lg[c]; }
        const float inv = frcp(sum);
        float* __restrict__ pr = pred + (size_t)(e0 + lane) * 10;
#pragma unroll
        for (int c = 0; c < 10; c++) pr[c] = lg[c] * inv;
    }
}

extern "C" void kernel_launch(void* const* d_in, const int* in_sizes, int n_in,
                              void* d_out, int out_size, void* d_ws, size_t ws_size,
                              hipStream_t stream) {
    const float* x    = (const float*)d_in[0];
    const float* eWih = (const float*)d_in[1];
    const float* eWhh = (const float*)d_in[2];
    const float* eb   = (const float*)d_in[3];
    const float* dWih = (const float*)d_in[4];
    const float* dWhh = (const float*)d_in[5];
    const float* db   = (const float*)d_in[6];
    const float* UW   = (const float*)d_in[7];
    const float* Ub   = (const float*)d_in[8];

    float* w    = (float*)d_ws;                      // 4544 floats used
    float* out  = (float*)d_out;
    float* pred = out + (size_t)B_TOTAL * T_STEPS * 28;

    repack_kernel<<<dim3(1), dim3(256), 0, stream>>>(eWih, eWhh, eb, dWih, dWhh, db, UW, Ub, w);
    lstm_main<<<dim3(B_TOTAL / 64), dim3(256), 0, stream>>>(x, w, out, pred);
}

// Round 4
// 903.112 us; speedup vs baseline: 1.2883x; 1.0265x over previous
//
#include <hip/hip_runtime.h>

#define B_TOTAL 65536
#define T_STEPS 28

typedef float f2 __attribute__((ext_vector_type(2)));

__device__ __forceinline__ float frcp(float x) { return __builtin_amdgcn_rcpf(x); }
__device__ __forceinline__ float sigf(float x) { return frcp(1.0f + __expf(-x)); }
__device__ __forceinline__ float tanhf_(float x) { return 2.0f * frcp(1.0f + __expf(-2.0f * x)) - 1.0f; }

// ---------------------------------------------------------------------------
// Repack weights into wave-uniform rows in d_ws.
// Row format (132 floats): [b_i b_f b_g b_o][Wi 0..31][Wf 0..31][Wg 0..31][Wo 0..31]
//   enc row k (k=0..3):   inputs = [x(28), he_prev(4)]  -> W*[j<28]=Wih, W*[28+j]=Whh
//   dec row k (rows 4..31): inputs = [hd(28), z(4)]     -> W*[j<28]=Whh, W*[28+j]=Wih
// U rows at float offset 4224, stride 32: [bias][UW 28][pad 3]
// Every gate sub-row starts at an even dword -> all weight PAIRS 8B aligned.
// ---------------------------------------------------------------------------
__global__ void repack_kernel(const float* __restrict__ eWih, const float* __restrict__ eWhh,
                              const float* __restrict__ eb,
                              const float* __restrict__ dWih, const float* __restrict__ dWhh,
                              const float* __restrict__ db,
                              const float* __restrict__ UW, const float* __restrict__ Ub,
                              float* __restrict__ w)
{
    const int p = threadIdx.x;
    for (int idx = p; idx < 4 * 132; idx += 256) {
        int k = idx / 132, r = idx % 132;
        float v;
        if (r < 4) v = eb[r * 4 + k];
        else {
            int g = (r - 4) / 32, j = (r - 4) % 32;
            v = (j < 28) ? eWih[(g * 4 + k) * 28 + j] : eWhh[(g * 4 + k) * 4 + (j - 28)];
        }
        w[k * 132 + r] = v;
    }
    for (int idx = p; idx < 28 * 132; idx += 256) {
        int k = idx / 132, r = idx % 132;
        float v;
        if (r < 4) v = db[r * 28 + k];
        else {
            int g = (r - 4) / 32, j = (r - 4) % 32;
            v = (j < 28) ? dWhh[(g * 28 + k) * 28 + j] : dWih[(g * 28 + k) * 4 + (j - 28)];
        }
        w[528 + k * 132 + r] = v;
    }
    for (int idx = p; idx < 10 * 32; idx += 256) {
        int c = idx / 32, r = idx % 32;
        float v = (r == 0) ? Ub[c] : ((r <= 28) ? UW[c * 28 + (r - 1)] : 0.f);
        w[4224 + c * 32 + r] = v;
    }
}

// ---------------------------------------------------------------------------
// LDS byte offsets. State tiles are [64 rows][30 dwords] (row stride 120 B,
// 8B-aligned rows; pair read at fixed j across 64 lanes is conflict-free).
// ---------------------------------------------------------------------------
#define XB   0        // x(t)           7680 B
#define HD0  7680     // decoder h, buf0
#define HD1  15360    // decoder h, buf1
#define HE   23040    // encoder h [2][64][4] floats, 2048 B
// total 25088 B

// Occupancy is LDS/grid-limited to 4 blocks/CU (= 4 waves/SIMD), so VGPRs up
// to 128 are free. waves_per_eu(4,4) pins the allocator budget to 128 and
// stops it from targeting 8 waves/SIMD (64 VGPR), which forced the f2 pairs
// to scratch in rounds 2-3 (FETCH 143 MB -> 880 MB signature).
__global__ void __launch_bounds__(256)
__attribute__((amdgpu_waves_per_eu(4, 4)))
lstm_main(const float* __restrict__ x, const float* __restrict__ w,
          float* __restrict__ out, float* __restrict__ pred)
{
    __shared__ char lb[25088];

    const int tid  = threadIdx.x;
    const int lane = tid & 63;
    const int s    = __builtin_amdgcn_readfirstlane(tid >> 6);
    const int e0   = blockIdx.x * 64;

    // block-coalesced staging map: idx = tid+256q -> (i = idx/28, k = idx%28)
    int goff[7], stb[7];
#pragma unroll
    for (int q = 0; q < 7; q++) {
        int idx = tid + 256 * q;
        int i = idx / 28;
        int k = idx - 28 * i;
        goff[q] = i * 784 + k;     // float offset in x / out block
        stb[q]  = i * 120 + k * 4; // byte offset in [64][30] LDS tile
    }

    const float* __restrict__ xblk = x + (size_t)e0 * 784;
    float* __restrict__ oblk       = out + (size_t)e0 * 784;

    // ---- prologue: stage x(0), zero hd0 + he[0] ----
#pragma unroll
    for (int q = 0; q < 7; q++)
        *(float*)(lb + XB + stb[q]) = xblk[goff[q]];
    for (int i2 = tid; i2 < 1920; i2 += 256) ((float*)(lb + HD0))[i2] = 0.f;
    ((float*)(lb + HE))[tid] = 0.f;   // he phase 0: 256 floats
    __syncthreads();

    const float* __restrict__ wenc = w + s * 132;
    const char* xrow = lb + XB + lane * 120;

    float ce = 0.f;
    float cd[7];
#pragma unroll
    for (int r = 0; r < 7; r++) cd[r] = 0.f;

    int hdc = HD0, hdn = HD1;

    for (int t = 0; t < T_STEPS; ++t) {
        const int p = t & 1;

        // ---- issue x(t+1) prefetch early (lands in phase 4.5) ----
        float xr[7];
        if (t < T_STEPS - 1) {
#pragma unroll
            for (int q = 0; q < 7; q++)
                xr[q] = xblk[goff[q] + (t + 1) * 28];
        }

        // ---- encoder unit s ----
        {
            const f2* xp2 = (const f2*)xrow;
            const f2 hep0 = *(const f2*)(lb + HE + p * 1024 + lane * 16);
            const f2 hep1 = *(const f2*)(lb + HE + p * 1024 + lane * 16 + 8);
            const f2* wg0 = (const f2*)(wenc + 4);
            const f2* wg1 = (const f2*)(wenc + 36);
            const f2* wg2 = (const f2*)(wenc + 68);
            const f2* wg3 = (const f2*)(wenc + 100);
            f2 a0 = {wenc[0], 0.f}, a1 = {wenc[1], 0.f};
            f2 a2 = {wenc[2], 0.f}, a3 = {wenc[3], 0.f};
#pragma unroll
            for (int j = 0; j < 14; j++) {
                const f2 v = xp2[j];
                a0 = __builtin_elementwise_fma(wg0[j], v, a0);
                a1 = __builtin_elementwise_fma(wg1[j], v, a1);
                a2 = __builtin_elementwise_fma(wg2[j], v, a2);
                a3 = __builtin_elementwise_fma(wg3[j], v, a3);
            }
            a0 = __builtin_elementwise_fma(wg0[14], hep0, a0);
            a1 = __builtin_elementwise_fma(wg1[14], hep0, a1);
            a2 = __builtin_elementwise_fma(wg2[14], hep0, a2);
            a3 = __builtin_elementwise_fma(wg3[14], hep0, a3);
            a0 = __builtin_elementwise_fma(wg0[15], hep1, a0);
            a1 = __builtin_elementwise_fma(wg1[15], hep1, a1);
            a2 = __builtin_elementwise_fma(wg2[15], hep1, a2);
            a3 = __builtin_elementwise_fma(wg3[15], hep1, a3);
            const float gi = a0.x + a0.y, gf = a1.x + a1.y;
            const float gg = a2.x + a2.y, go = a3.x + a3.y;
            ce = sigf(gf) * ce + sigf(gi) * tanhf_(gg);
            *(float*)(lb + HE + (p ^ 1) * 1024 + lane * 16 + s * 4) =
                sigf(go) * tanhf_(ce);
        }
        __syncthreads();   // barrier A: he(t) ready; xBuf(t) reads done

        // ---- decoder rows s*7 .. s*7+6 ----
        {
            const f2 hz0 = *(const f2*)(lb + HE + (p ^ 1) * 1024 + lane * 16);
            const f2 hz1 = *(const f2*)(lb + HE + (p ^ 1) * 1024 + lane * 16 + 8);
            const f2* hc2 = (const f2*)(lb + hdc + lane * 120);
            f2 hv[14];
#pragma unroll
            for (int j = 0; j < 14; j++) hv[j] = hc2[j];
            char* hwr = lb + hdn + lane * 120 + s * 28;   // rows s*7..s*7+6
#pragma unroll
            for (int r = 0; r < 7; r++) {
                const float* __restrict__ wrow = w + 528 + (s * 7 + r) * 132;
                const f2* wg0 = (const f2*)(wrow + 4);
                const f2* wg1 = (const f2*)(wrow + 36);
                const f2* wg2 = (const f2*)(wrow + 68);
                const f2* wg3 = (const f2*)(wrow + 100);
                f2 a0 = {wrow[0], 0.f}, a1 = {wrow[1], 0.f};
                f2 a2 = {wrow[2], 0.f}, a3 = {wrow[3], 0.f};
#pragma unroll
                for (int j = 0; j < 14; j++) {
                    const f2 v = hv[j];
                    a0 = __builtin_elementwise_fma(wg0[j], v, a0);
                    a1 = __builtin_elementwise_fma(wg1[j], v, a1);
                    a2 = __builtin_elementwise_fma(wg2[j], v, a2);
                    a3 = __builtin_elementwise_fma(wg3[j], v, a3);
                }
                a0 = __builtin_elementwise_fma(wg0[14], hz0, a0);
                a1 = __builtin_elementwise_fma(wg1[14], hz0, a1);
                a2 = __builtin_elementwise_fma(wg2[14], hz0, a2);
                a3 = __builtin_elementwise_fma(wg3[14], hz0, a3);
                a0 = __builtin_elementwise_fma(wg0[15], hz1, a0);
                a1 = __builtin_elementwise_fma(wg1[15], hz1, a1);
                a2 = __builtin_elementwise_fma(wg2[15], hz1, a2);
                a3 = __builtin_elementwise_fma(wg3[15], hz1, a3);
                const float gi = a0.x + a0.y, gf = a1.x + a1.y;
                const float gg = a2.x + a2.y, go = a3.x + a3.y;
                const float cc = sigf(gf) * cd[r] + sigf(gi) * tanhf_(gg);
                cd[r] = cc;
                *(float*)(hwr + r * 4) = sigf(go) * tanhf_(cc);
            }
        }

        // ---- land x(t+1) (xBuf reads ended at barrier A) ----
        if (t < T_STEPS - 1) {
#pragma unroll
            for (int q = 0; q < 7; q++)
                *(float*)(lb + XB + stb[q]) = xr[q];
        }
        __syncthreads();   // barrier B: hd(t) + xBuf(t+1) complete

        // ---- coalesced out store ----
        {
            const char* hsrc = lb + hdn;
#pragma unroll
            for (int q = 0; q < 7; q++)
                oblk[goff[q] + t * 28] = *(const float*)(hsrc + stb[q]);
        }
        const int tmp = hdc; hdc = hdn; hdn = tmp;
    }

    // ---- final projection + softmax (wave 0 only); final h is in `hdc` ----
    if (s == 0) {
        float hf[28];
        const f2* hc2 = (const f2*)(lb + hdc + lane * 120);
#pragma unroll
        for (int j = 0; j < 14; j++) {
            const f2 hp = hc2[j];
            hf[2 * j] = hp.x; hf[2 * j + 1] = hp.y;
        }
        float lg[10];
#pragma unroll
        for (int c = 0; c < 10; c++) {
            const float* __restrict__ ur = w + 4224 + c * 32;
            float a = ur[0];
#pragma unroll
            for (int j = 0; j < 28; j++) a = fmaf(ur[1 + j], hf[j], a);
            lg[c] = a;
        }
        float m = lg[0];
#pragma unroll
        for (int c = 1; c < 10; c++) m = fmaxf(m, lg[c]);
        float sum = 0.f;
#pragma unroll
        for (int c = 0; c < 10; c++) { lg[c] = __expf(lg[c] - m); sum += lg[c]; }
        const float inv = frcp(sum);
        float* __restrict__ pr = pred + (size_t)(e0 + lane) * 10;
#pragma unroll
        for (int c = 0; c < 10; c++) pr[c] = lg[c] * inv;
    }
}

extern "C" void kernel_launch(void* const* d_in, const int* in_sizes, int n_in,
                              void* d_out, int out_size, void* d_ws, size_t ws_size,
                              hipStream_t stream) {
    const float* x    = (const float*)d_in[0];
    const float* eWih = (const float*)d_in[1];
    const float* eWhh = (const float*)d_in[2];
    const float* eb   = (const float*)d_in[3];
    const float* dWih = (const float*)d_in[4];
    const float* dWhh = (const float*)d_in[5];
    const float* db   = (const float*)d_in[6];
    const float* UW   = (const float*)d_in[7];
    const float* Ub   = (const float*)d_in[8];

    float* w    = (float*)d_ws;                      // 4544 floats used
    float* out  = (float*)d_out;
    float* pred = out + (size_t)B_TOTAL * T_STEPS * 28;

    repack_kernel<<<dim3(1), dim3(256), 0, stream>>>(eWih, eWhh, eb, dWih, dWhh, db, UW, Ub, w);
    lstm_main<<<dim3(B_TOTAL / 64), dim3(256), 0, stream>>>(x, w, out, pred);
}

// Round 5
// 542.034 us; speedup vs baseline: 2.1466x; 1.6662x over previous
//
#include <hip/hip_runtime.h>

#define B_TOTAL 65536
#define T_STEPS 28

typedef float f2 __attribute__((ext_vector_type(2)));

__device__ __forceinline__ float frcp(float x) { return __builtin_amdgcn_rcpf(x); }
__device__ __forceinline__ float sigf(float x) { return frcp(1.0f + __expf(-x)); }
__device__ __forceinline__ float tanhf_(float x) { return 2.0f * frcp(1.0f + __expf(-2.0f * x)) - 1.0f; }

// ---------------------------------------------------------------------------
// Repack weights into wave-uniform rows in d_ws.
// Row format (132 floats): [b_i b_f b_g b_o][Wi 0..31][Wf 0..31][Wg 0..31][Wo 0..31]
//   enc row k (k=0..3):   inputs = [x(28), he_prev(4)]  -> W*[j<28]=Wih, W*[28+j]=Whh
//   dec row k (rows 4..31): inputs = [hd(28), z(4)]     -> W*[j<28]=Whh, W*[28+j]=Wih
// U rows at float offset 4224, stride 32: [bias][UW 28][pad 3]
// Every gate sub-row starts at an even dword -> all weight PAIRS 8B aligned
// (and even-SGPR-pair aligned once the compiler scalarizes them).
// ---------------------------------------------------------------------------
__global__ void repack_kernel(const float* __restrict__ eWih, const float* __restrict__ eWhh,
                              const float* __restrict__ eb,
                              const float* __restrict__ dWih, const float* __restrict__ dWhh,
                              const float* __restrict__ db,
                              const float* __restrict__ UW, const float* __restrict__ Ub,
                              float* __restrict__ w)
{
    const int p = threadIdx.x;
    for (int idx = p; idx < 4 * 132; idx += 256) {
        int k = idx / 132, r = idx % 132;
        float v;
        if (r < 4) v = eb[r * 4 + k];
        else {
            int g = (r - 4) / 32, j = (r - 4) % 32;
            v = (j < 28) ? eWih[(g * 4 + k) * 28 + j] : eWhh[(g * 4 + k) * 4 + (j - 28)];
        }
        w[k * 132 + r] = v;
    }
    for (int idx = p; idx < 28 * 132; idx += 256) {
        int k = idx / 132, r = idx % 132;
        float v;
        if (r < 4) v = db[r * 28 + k];
        else {
            int g = (r - 4) / 32, j = (r - 4) % 32;
            v = (j < 28) ? dWhh[(g * 28 + k) * 28 + j] : dWih[(g * 28 + k) * 4 + (j - 28)];
        }
        w[528 + k * 132 + r] = v;
    }
    for (int idx = p; idx < 10 * 32; idx += 256) {
        int c = idx / 32, r = idx % 32;
        float v = (r == 0) ? Ub[c] : ((r <= 28) ? UW[c * 28 + (r - 1)] : 0.f);
        w[4224 + c * 32 + r] = v;
    }
}

// ---------------------------------------------------------------------------
// LDS byte offsets. State tiles are [64 rows][30 dwords] (row stride 120 B,
// 8B-aligned rows; wave64 pair read at fixed j hits the unavoidable
// 4-dwords-per-bank floor of b64 -> no extra serialization).
// ---------------------------------------------------------------------------
#define XB   0        // x(t)           7680 B
#define HD0  7680     // decoder h, buf0
#define HD1  15360    // decoder h, buf1
#define HE   23040    // encoder h [2][64][4] floats, 2048 B
// total 25088 B

// Register budget discipline (the allocator targets 64 VGPRs no matter what
// occupancy hints say — rounds 2-4 evidence): decoder inputs are STREAMED
// from LDS per row, never held as a 14xf2 array. The asm memory clobber at
// each row top stops CSE from re-materializing that array (which is what
// forced the 875 MB scratch-spill signature in rounds 2-4).
__global__ __launch_bounds__(256, 4)
void lstm_main(const float* __restrict__ x, const float* __restrict__ w,
               float* __restrict__ out, float* __restrict__ pred)
{
    __shared__ char lb[25088];

    const int tid  = threadIdx.x;
    const int lane = tid & 63;
    const int s    = __builtin_amdgcn_readfirstlane(tid >> 6);
    const int e0   = blockIdx.x * 64;

    // block-coalesced staging map: idx = tid+256q -> (i = idx/28, k = idx%28)
    int goff[7], stb[7];
#pragma unroll
    for (int q = 0; q < 7; q++) {
        int idx = tid + 256 * q;
        int i = idx / 28;
        int k = idx - 28 * i;
        goff[q] = i * 784 + k;     // float offset in x / out block
        stb[q]  = i * 120 + k * 4; // byte offset in [64][30] LDS tile
    }

    const float* __restrict__ xblk = x + (size_t)e0 * 784;
    float* __restrict__ oblk       = out + (size_t)e0 * 784;

    // ---- prologue: stage x(0), zero hd0 + he[0] ----
#pragma unroll
    for (int q = 0; q < 7; q++)
        *(float*)(lb + XB + stb[q]) = xblk[goff[q]];
    for (int i2 = tid; i2 < 1920; i2 += 256) ((float*)(lb + HD0))[i2] = 0.f;
    ((float*)(lb + HE))[tid] = 0.f;   // he phase 0: 256 floats
    __syncthreads();

    const float* __restrict__ wenc = w + s * 132;
    const char* xrow = lb + XB + lane * 120;

    float ce = 0.f;
    float cd[7];
#pragma unroll
    for (int r = 0; r < 7; r++) cd[r] = 0.f;

    int hdc = HD0, hdn = HD1;

    for (int t = 0; t < T_STEPS; ++t) {
        const int p = t & 1;

        // ---- issue x(t+1) prefetch early (lands in phase 4.5) ----
        float xr[7];
        if (t < T_STEPS - 1) {
#pragma unroll
            for (int q = 0; q < 7; q++)
                xr[q] = xblk[goff[q] + (t + 1) * 28];
        }

        // ---- encoder unit s ----
        {
            const f2* xp2 = (const f2*)xrow;
            const f2 hep0 = *(const f2*)(lb + HE + p * 1024 + lane * 16);
            const f2 hep1 = *(const f2*)(lb + HE + p * 1024 + lane * 16 + 8);
            const f2* wg0 = (const f2*)(wenc + 4);
            const f2* wg1 = (const f2*)(wenc + 36);
            const f2* wg2 = (const f2*)(wenc + 68);
            const f2* wg3 = (const f2*)(wenc + 100);
            f2 a0 = {wenc[0], 0.f}, a1 = {wenc[1], 0.f};
            f2 a2 = {wenc[2], 0.f}, a3 = {wenc[3], 0.f};
#pragma unroll
            for (int j = 0; j < 14; j++) {
                const f2 v = xp2[j];
                a0 = __builtin_elementwise_fma(wg0[j], v, a0);
                a1 = __builtin_elementwise_fma(wg1[j], v, a1);
                a2 = __builtin_elementwise_fma(wg2[j], v, a2);
                a3 = __builtin_elementwise_fma(wg3[j], v, a3);
            }
            a0 = __builtin_elementwise_fma(wg0[14], hep0, a0);
            a1 = __builtin_elementwise_fma(wg1[14], hep0, a1);
            a2 = __builtin_elementwise_fma(wg2[14], hep0, a2);
            a3 = __builtin_elementwise_fma(wg3[14], hep0, a3);
            a0 = __builtin_elementwise_fma(wg0[15], hep1, a0);
            a1 = __builtin_elementwise_fma(wg1[15], hep1, a1);
            a2 = __builtin_elementwise_fma(wg2[15], hep1, a2);
            a3 = __builtin_elementwise_fma(wg3[15], hep1, a3);
            const float gi = a0.x + a0.y, gf = a1.x + a1.y;
            const float gg = a2.x + a2.y, go = a3.x + a3.y;
            ce = sigf(gf) * ce + sigf(gi) * tanhf_(gg);
            *(float*)(lb + HE + (p ^ 1) * 1024 + lane * 16 + s * 4) =
                sigf(go) * tanhf_(ce);
        }
        __syncthreads();   // barrier A: he(t) ready; xBuf(t) reads done

        // ---- decoder rows s*7 .. s*7+6 (inputs streamed from LDS per row) ----
        {
            const f2 hz0 = *(const f2*)(lb + HE + (p ^ 1) * 1024 + lane * 16);
            const f2 hz1 = *(const f2*)(lb + HE + (p ^ 1) * 1024 + lane * 16 + 8);
            const char* hcr = lb + hdc + lane * 120;
            char* hwr = lb + hdn + lane * 120 + s * 28;   // rows s*7..s*7+6
#pragma unroll
            for (int r = 0; r < 7; r++) {
                asm volatile("" ::: "memory");   // block cross-row CSE of LDS reads
                const float* __restrict__ wrow = w + 528 + (s * 7 + r) * 132;
                const f2* wg0 = (const f2*)(wrow + 4);
                const f2* wg1 = (const f2*)(wrow + 36);
                const f2* wg2 = (const f2*)(wrow + 68);
                const f2* wg3 = (const f2*)(wrow + 100);
                const f2* hc2 = (const f2*)hcr;
                f2 a0 = {wrow[0], 0.f}, a1 = {wrow[1], 0.f};
                f2 a2 = {wrow[2], 0.f}, a3 = {wrow[3], 0.f};
#pragma unroll
                for (int j = 0; j < 14; j++) {
                    const f2 v = hc2[j];
                    a0 = __builtin_elementwise_fma(wg0[j], v, a0);
                    a1 = __builtin_elementwise_fma(wg1[j], v, a1);
                    a2 = __builtin_elementwise_fma(wg2[j], v, a2);
                    a3 = __builtin_elementwise_fma(wg3[j], v, a3);
                }
                a0 = __builtin_elementwise_fma(wg0[14], hz0, a0);
                a1 = __builtin_elementwise_fma(wg1[14], hz0, a1);
                a2 = __builtin_elementwise_fma(wg2[14], hz0, a2);
                a3 = __builtin_elementwise_fma(wg3[14], hz0, a3);
                a0 = __builtin_elementwise_fma(wg0[15], hz1, a0);
                a1 = __builtin_elementwise_fma(wg1[15], hz1, a1);
                a2 = __builtin_elementwise_fma(wg2[15], hz1, a2);
                a3 = __builtin_elementwise_fma(wg3[15], hz1, a3);
                const float gi = a0.x + a0.y, gf = a1.x + a1.y;
                const float gg = a2.x + a2.y, go = a3.x + a3.y;
                const float cc = sigf(gf) * cd[r] + sigf(gi) * tanhf_(gg);
                cd[r] = cc;
                *(float*)(hwr + r * 4) = sigf(go) * tanhf_(cc);
            }
        }

        // ---- land x(t+1) (xBuf reads ended at barrier A) ----
        if (t < T_STEPS - 1) {
#pragma unroll
            for (int q = 0; q < 7; q++)
                *(float*)(lb + XB + stb[q]) = xr[q];
        }
        __syncthreads();   // barrier B: hd(t) + xBuf(t+1) complete

        // ---- coalesced out store ----
        {
            const char* hsrc = lb + hdn;
#pragma unroll
            for (int q = 0; q < 7; q++)
                oblk[goff[q] + t * 28] = *(const float*)(hsrc + stb[q]);
        }
        const int tmp = hdc; hdc = hdn; hdn = tmp;
    }

    // ---- final projection + softmax (wave 0 only); final h is in `hdc` ----
    if (s == 0) {
        float hf[28];
        const f2* hc2 = (const f2*)(lb + hdc + lane * 120);
#pragma unroll
        for (int j = 0; j < 14; j++) {
            const f2 hp = hc2[j];
            hf[2 * j] = hp.x; hf[2 * j + 1] = hp.y;
        }
        float lg[10];
#pragma unroll
        for (int c = 0; c < 10; c++) {
            const float* __restrict__ ur = w + 4224 + c * 32;
            float a = ur[0];
#pragma unroll
            for (int j = 0; j < 28; j++) a = fmaf(ur[1 + j], hf[j], a);
            lg[c] = a;
        }
        float m = lg[0];
#pragma unroll
        for (int c = 1; c < 10; c++) m = fmaxf(m, lg[c]);
        float sum = 0.f;
#pragma unroll
        for (int c = 0; c < 10; c++) { lg[c] = __expf(lg[c] - m); sum += lg[c]; }
        const float inv = frcp(sum);
        float* __restrict__ pr = pred + (size_t)(e0 + lane) * 10;
#pragma unroll
        for (int c = 0; c < 10; c++) pr[c] = lg[c] * inv;
    }
}

extern "C" void kernel_launch(void* const* d_in, const int* in_sizes, int n_in,
                              void* d_out, int out_size, void* d_ws, size_t ws_size,
                              hipStream_t stream) {
    const float* x    = (const float*)d_in[0];
    const float* eWih = (const float*)d_in[1];
    const float* eWhh = (const float*)d_in[2];
    const float* eb   = (const float*)d_in[3];
    const float* dWih = (const float*)d_in[4];
    const float* dWhh = (const float*)d_in[5];
    const float* db   = (const float*)d_in[6];
    const float* UW   = (const float*)d_in[7];
    const float* Ub   = (const float*)d_in[8];

    float* w    = (float*)d_ws;                      // 4544 floats used
    float* out  = (float*)d_out;
    float* pred = out + (size_t)B_TOTAL * T_STEPS * 28;

    repack_kernel<<<dim3(1), dim3(256), 0, stream>>>(eWih, eWhh, eb, dWih, dWhh, db, UW, Ub, w);
    lstm_main<<<dim3(B_TOTAL / 64), dim3(256), 0, stream>>>(x, w, out, pred);
}

// Round 7
// 517.688 us; speedup vs baseline: 2.2475x; 1.0470x over previous
//
#include <hip/hip_runtime.h>

#define B_TOTAL 65536
#define T_STEPS 28

typedef float f2 __attribute__((ext_vector_type(2)));

__device__ __forceinline__ float frcp(float x) { return __builtin_amdgcn_rcpf(x); }
__device__ __forceinline__ float sigf(float x) { return frcp(1.0f + __expf(-x)); }
__device__ __forceinline__ float tanhf_(float x) { return 2.0f * frcp(1.0f + __expf(-2.0f * x)) - 1.0f; }

// Raw workgroup barrier: waits LDS ops only. Unlike __syncthreads(), does NOT
// drain vmcnt -> in-flight out-stores / x-prefetch loads keep flying across
// the barrier (the compiler still inserts its own vmcnt waits before any USE
// of a load result). Memory clobber stops LDS ops migrating across.
__device__ __forceinline__ void bar_lds() {
    asm volatile("s_waitcnt lgkmcnt(0)\n\ts_barrier" ::: "memory");
}

// ---------------------------------------------------------------------------
// Repack weights into wave-uniform rows in d_ws (unchanged from round 5).
// Row format (132 floats): [b_i b_f b_g b_o][Wi 0..31][Wf 0..31][Wg 0..31][Wo 0..31]
//   enc row k (k=0..3):   inputs = [x(28), he_prev(4)]  -> W*[j<28]=Wih, W*[28+j]=Whh
//   dec row k (rows 4..31): inputs = [hd(28), z(4)]     -> W*[j<28]=Whh, W*[28+j]=Wih
// U rows at float offset 4224, stride 32: [bias][UW 28][pad 3]
// ---------------------------------------------------------------------------
__global__ void repack_kernel(const float* __restrict__ eWih, const float* __restrict__ eWhh,
                              const float* __restrict__ eb,
                              const float* __restrict__ dWih, const float* __restrict__ dWhh,
                              const float* __restrict__ db,
                              const float* __restrict__ UW, const float* __restrict__ Ub,
                              float* __restrict__ w)
{
    const int p = threadIdx.x;
    for (int idx = p; idx < 4 * 132; idx += 256) {
        int k = idx / 132, r = idx % 132;
        float v;
        if (r < 4) v = eb[r * 4 + k];
        else {
            int g = (r - 4) / 32, j = (r - 4) % 32;
            v = (j < 28) ? eWih[(g * 4 + k) * 28 + j] : eWhh[(g * 4 + k) * 4 + (j - 28)];
        }
        w[k * 132 + r] = v;
    }
    for (int idx = p; idx < 28 * 132; idx += 256) {
        int k = idx / 132, r = idx % 132;
        float v;
        if (r < 4) v = db[r * 28 + k];
        else {
            int g = (r - 4) / 32, j = (r - 4) % 32;
            v = (j < 28) ? dWhh[(g * 28 + k) * 28 + j] : dWih[(g * 28 + k) * 4 + (j - 28)];
        }
        w[528 + k * 132 + r] = v;
    }
    for (int idx = p; idx < 10 * 32; idx += 256) {
        int c = idx / 32, r = idx % 32;
        float v = (r == 0) ? Ub[c] : ((r <= 28) ? UW[c * 28 + (r - 1)] : 0.f);
        w[4224 + c * 32 + r] = v;
    }
}

// ---------------------------------------------------------------------------
// LDS byte offsets. State tiles [64 rows][30 dwords] (stride 120 B).
// Single barrier per timestep: encoder is pipelined one step ahead, so every
// cross-wave handoff is write-in-slot-k -> read-in-slot-(k+1).
//   x(t)  lives in xbuf[t&1];  hd(t) in hdbuf[t&1];  he(t) in hebuf[t&1].
// ---------------------------------------------------------------------------
#define XA   0        // x buf parity 0, 7680 B
#define XB1  7680     // x buf parity 1
#define HDA  15360    // hd buf parity 0
#define HDB  23040    // hd buf parity 1
#define HEA  30720    // he buf parity 0: [64][4] floats, 1024 B
#define HEB  31744    // he buf parity 1
// total 32768 B -> 4 blocks/CU (grid-capped at 4 anyway)

__global__ __launch_bounds__(256, 4)
void lstm_main(const float* __restrict__ x, const float* __restrict__ w,
               float* __restrict__ out, float* __restrict__ pred)
{
    __shared__ char lb[32768];

    const int tid  = threadIdx.x;
    const int lane = tid & 63;
    const int s    = __builtin_amdgcn_readfirstlane(tid >> 6);
    const int e0   = blockIdx.x * 64;

    // block-coalesced staging map: idx = tid+256q -> (i = idx/28, k = idx%28)
    int goff[7], stb[7];
#pragma unroll
    for (int q = 0; q < 7; q++) {
        int idx = tid + 256 * q;
        int i = idx / 28;
        int k = idx - 28 * i;
        goff[q] = i * 784 + k;     // float offset in x / out block
        stb[q]  = i * 120 + k * 4; // byte offset in [64][30] LDS tile
    }

    const float* __restrict__ xblk = x + (size_t)e0 * 784;
    float* __restrict__ oblk       = out + (size_t)e0 * 784;

    const float* __restrict__ wenc = w + s * 132;

    float ce = 0.f;
    float cd[7];
#pragma unroll
    for (int r = 0; r < 7; r++) cd[r] = 0.f;

    // encoder step for time tx: reads x(tx) from xbase, he(tx-1) from hrd;
    // writes he(tx) to hwr. ce advances by one step per call.
    auto enc_step = [&](const int xbase, const int hrd, const int hwr) {
        const f2* xp2 = (const f2*)(lb + xbase + lane * 120);
        const f2 hep0 = *(const f2*)(lb + hrd + lane * 16);
        const f2 hep1 = *(const f2*)(lb + hrd + lane * 16 + 8);
        const f2* wg0 = (const f2*)(wenc + 4);
        const f2* wg1 = (const f2*)(wenc + 36);
        const f2* wg2 = (const f2*)(wenc + 68);
        const f2* wg3 = (const f2*)(wenc + 100);
        f2 a0 = {wenc[0], 0.f}, a1 = {wenc[1], 0.f};
        f2 a2 = {wenc[2], 0.f}, a3 = {wenc[3], 0.f};
#pragma unroll
        for (int j = 0; j < 14; j++) {
            const f2 v = xp2[j];
            a0 = __builtin_elementwise_fma(wg0[j], v, a0);
            a1 = __builtin_elementwise_fma(wg1[j], v, a1);
            a2 = __builtin_elementwise_fma(wg2[j], v, a2);
            a3 = __builtin_elementwise_fma(wg3[j], v, a3);
        }
        a0 = __builtin_elementwise_fma(wg0[14], hep0, a0);
        a1 = __builtin_elementwise_fma(wg1[14], hep0, a1);
        a2 = __builtin_elementwise_fma(wg2[14], hep0, a2);
        a3 = __builtin_elementwise_fma(wg3[14], hep0, a3);
        a0 = __builtin_elementwise_fma(wg0[15], hep1, a0);
        a1 = __builtin_elementwise_fma(wg1[15], hep1, a1);
        a2 = __builtin_elementwise_fma(wg2[15], hep1, a2);
        a3 = __builtin_elementwise_fma(wg3[15], hep1, a3);
        const float gi = a0.x + a0.y, gf = a1.x + a1.y;
        const float gg = a2.x + a2.y, go = a3.x + a3.y;
        ce = sigf(gf) * ce + sigf(gi) * tanhf_(gg);
        *(float*)(lb + hwr + lane * 16 + s * 4) = sigf(go) * tanhf_(ce);
    };

    // ---- prologue: stage x(0)->XA, x(1)->XB1; zero hd(-1)=HDB, he(-1)=HEB ----
#pragma unroll
    for (int q = 0; q < 7; q++) {
        *(float*)(lb + XA  + stb[q]) = xblk[goff[q]];
        *(float*)(lb + XB1 + stb[q]) = xblk[goff[q] + 28];
    }
    for (int i2 = tid; i2 < 1920; i2 += 256) ((float*)(lb + HDB))[i2] = 0.f;
    ((float*)(lb + HEB))[tid] = 0.f;
    bar_lds();

    enc_step(XA, HEB, HEA);   // he(0) -> HEA
    bar_lds();

    // slot-0 state: dec(0) reads hd(-1)=HDB, he(0)=HEA, writes hd(0)=HDA;
    // enc(1) reads x(1)=XB1; stage x(2)->XA.
    int hdc = HDB, hdn = HDA;   // dec read / dec write
    int her = HEA, hew = HEB;   // he(t) / he(t+1)
    int xe  = XB1, xw  = XA;    // enc-read x(t+1) / stage-target x(t+2)

    for (int t = 0; t < T_STEPS; ++t) {
        // ---- issue x(t+2) global loads first (latency hidden under dec+enc) ----
        float xr[7];
        if (t < T_STEPS - 2) {
#pragma unroll
            for (int q = 0; q < 7; q++)
                xr[q] = xblk[goff[q] + (t + 2) * 28];
        }

        // ---- decoder(t): z = he(t) [her], hd(t-1) [hdc] -> hd(t) [hdn] ----
        {
            const f2 hz0 = *(const f2*)(lb + her + lane * 16);
            const f2 hz1 = *(const f2*)(lb + her + lane * 16 + 8);
            const char* hcr = lb + hdc + lane * 120;
            char* hwrp = lb + hdn + lane * 120 + s * 28;   // rows s*7..s*7+6
#pragma unroll
            for (int r = 0; r < 7; r++) {
                asm volatile("" ::: "memory");   // block cross-row CSE of LDS reads
                const float* __restrict__ wrow = w + 528 + (s * 7 + r) * 132;
                const f2* wg0 = (const f2*)(wrow + 4);
                const f2* wg1 = (const f2*)(wrow + 36);
                const f2* wg2 = (const f2*)(wrow + 68);
                const f2* wg3 = (const f2*)(wrow + 100);
                const f2* hc2 = (const f2*)hcr;
                f2 a0 = {wrow[0], 0.f}, a1 = {wrow[1], 0.f};
                f2 a2 = {wrow[2], 0.f}, a3 = {wrow[3], 0.f};
#pragma unroll
                for (int j = 0; j < 14; j++) {
                    const f2 v = hc2[j];
                    a0 = __builtin_elementwise_fma(wg0[j], v, a0);
                    a1 = __builtin_elementwise_fma(wg1[j], v, a1);
                    a2 = __builtin_elementwise_fma(wg2[j], v, a2);
                    a3 = __builtin_elementwise_fma(wg3[j], v, a3);
                }
                a0 = __builtin_elementwise_fma(wg0[14], hz0, a0);
                a1 = __builtin_elementwise_fma(wg1[14], hz0, a1);
                a2 = __builtin_elementwise_fma(wg2[14], hz0, a2);
                a3 = __builtin_elementwise_fma(wg3[14], hz0, a3);
                a0 = __builtin_elementwise_fma(wg0[15], hz1, a0);
                a1 = __builtin_elementwise_fma(wg1[15], hz1, a1);
                a2 = __builtin_elementwise_fma(wg2[15], hz1, a2);
                a3 = __builtin_elementwise_fma(wg3[15], hz1, a3);
                const float gi = a0.x + a0.y, gf = a1.x + a1.y;
                const float gg = a2.x + a2.y, go = a3.x + a3.y;
                const float cc = sigf(gf) * cd[r] + sigf(gi) * tanhf_(gg);
                cd[r] = cc;
                *(float*)(hwrp + r * 4) = sigf(go) * tanhf_(cc);
            }
        }

        // ---- encoder(t+1): x(t+1) [xe], he(t) [her] -> he(t+1) [hew] ----
        if (t < T_STEPS - 1) enc_step(xe, her, hew);

        // ---- out(t-1): hd(t-1) tile [hdc] is stable this slot ----
        if (t >= 1) {
            const char* hsrc = lb + hdc;
#pragma unroll
            for (int q = 0; q < 7; q++)
                oblk[goff[q] + (t - 1) * 28] = *(const float*)(hsrc + stb[q]);
        }

        // ---- land x(t+2) into xw (its last readers finished in slot t-1) ----
        if (t < T_STEPS - 2) {
#pragma unroll
            for (int q = 0; q < 7; q++)
                *(float*)(lb + xw + stb[q]) = xr[q];
        }

        bar_lds();   // single barrier: all slot-k writes -> slot-(k+1) reads

        int tmp;
        tmp = hdc; hdc = hdn; hdn = tmp;
        tmp = her; her = hew; hew = tmp;
        tmp = xe;  xe  = xw;  xw  = tmp;
    }

    // ---- out(27): hd(27) is in hdc after the final swap ----
    {
        const char* hsrc = lb + hdc;
#pragma unroll
        for (int q = 0; q < 7; q++)
            oblk[goff[q] + 27 * 28] = *(const float*)(hsrc + stb[q]);
    }

    // ---- final projection + softmax (wave 0 only) ----
    if (s == 0) {
        float hf[28];
        const f2* hc2 = (const f2*)(lb + hdc + lane * 120);
#pragma unroll
        for (int j = 0; j < 14; j++) {
            const f2 hp = hc2[j];
            hf[2 * j] = hp.x; hf[2 * j + 1] = hp.y;
        }
        float lg[10];
#pragma unroll
        for (int c = 0; c < 10; c++) {
            const float* __restrict__ ur = w + 4224 + c * 32;
            float a = ur[0];
#pragma unroll
            for (int j = 0; j < 28; j++) a = fmaf(ur[1 + j], hf[j], a);
            lg[c] = a;
        }
        float m = lg[0];
#pragma unroll
        for (int c = 1; c < 10; c++) m = fmaxf(m, lg[c]);
        float sum = 0.f;
#pragma unroll
        for (int c = 0; c < 10; c++) { lg[c] = __expf(lg[c] - m); sum += lg[c]; }
        const float inv = frcp(sum);
        float* __restrict__ pr = pred + (size_t)(e0 + lane) * 10;
#pragma unroll
        for (int c = 0; c < 10; c++) pr[c] = lg[c] * inv;
    }
}

extern "C" void kernel_launch(void* const* d_in, const int* in_sizes, int n_in,
                              void* d_out, int out_size, void* d_ws, size_t ws_size,
                              hipStream_t stream) {
    const float* x    = (const float*)d_in[0];
    const float* eWih = (const float*)d_in[1];
    const float* eWhh = (const float*)d_in[2];
    const float* eb   = (const float*)d_in[3];
    const float* dWih = (const float*)d_in[4];
    const float* dWhh = (const float*)d_in[5];
    const float* db   = (const float*)d_in[6];
    const float* UW   = (const float*)d_in[7];
    const float* Ub   = (const float*)d_in[8];

    float* w    = (float*)d_ws;                      // 4544 floats used
    float* out  = (float*)d_out;
    float* pred = out + (size_t)B_TOTAL * T_STEPS * 28;

    repack_kernel<<<dim3(1), dim3(256), 0, stream>>>(eWih, eWhh, eb, dWih, dWhh, db, UW, Ub, w);
    lstm_main<<<dim3(B_TOTAL / 64), dim3(256), 0, stream>>>(x, w, out, pred);
}